// Round 15
// baseline (514.534 us; speedup 1.0000x reference)
//
#include <hip/hip_runtime.h>

// ---------------------------------------------------------------------------
// DFTB layer, round 13.
//  K1 netvals / K2 rot / K3 coulomb / K4 erep  (unchanged)
//  K5 k_ns  : NS S^{-1/2} (6 mm) + fockp = X F X + C2 = X E S X (4 mm)
//  K6 k_jac : split-row XOR-block Jacobi + split epilogue (r12-measured,
//             no spill). Round-13 changes INSIDE the sweep loop only:
//              - three-shear rotation (exact, 3 FMA/elem-pair vs 4 VALU)
//              - 4-way split gamma/norm chains (latency 128cy -> ~40cy)
//              - native v_rcp/v_rsq for the angle chain (self-correcting)
//              - sweeps 4 -> 3 (absmax bit-identical at 5 and 4 sweeps;
//                pre-commit: revert to 4 if absmax degrades)
// ---------------------------------------------------------------------------

#define NMOLC 2048
#define NSPC  500000
#define L0C   100000
#define NROTC 200000
#define NREPC 500000
#define MS 68   // LDS row stride for k_ns matmul buffers

// ---------------- K1: net_vals = A @ coeffs + b ----------------
__global__ __launch_bounds__(256) void k_netvals(const float* __restrict__ A,
                                                 const float* __restrict__ b,
                                                 const float* __restrict__ coeffs,
                                                 float* __restrict__ net){
  int gid = blockIdx.x * 256 + threadIdx.x;
  int row = gid >> 4;
  int l   = gid & 15;
  if (row >= NSPC) return;
  float4 c4 = reinterpret_cast<const float4*>(coeffs)[l];
  float4 a4 = reinterpret_cast<const float4*>(A)[(size_t)row * 16 + l];
  float s = a4.x*c4.x + a4.y*c4.y + a4.z*c4.z + a4.w*c4.w;
  s += __shfl_xor(s, 1, 16);
  s += __shfl_xor(s, 2, 16);
  s += __shfl_xor(s, 4, 16);
  s += __shfl_xor(s, 8, 16);
  if (l == 0) net[row] = s + b[row];
}

// ---------------- K2: rot_out = [0,1] ++ direct ++ rotated ----------------
__global__ __launch_bounds__(256) void k_rot(const float* __restrict__ net,
                                             const float* __restrict__ rot_tensor,
                                             const int* __restrict__ g_rot_direct,
                                             const int* __restrict__ g_rot,
                                             float* __restrict__ rot_out){
  int gid = blockIdx.x * 256 + threadIdx.x;
  if (gid == 0){ rot_out[0] = 0.f; rot_out[1] = 1.f; }
  if (gid < L0C){
    rot_out[2 + gid] = net[g_rot_direct[gid]];
  }
  int n = gid - L0C;
  if (n >= 0 && n < NROTC){
    float v0 = net[g_rot[3*n    ]];
    float v1 = net[g_rot[3*n + 1]];
    float v2 = net[g_rot[3*n + 2]];
    const float* R = rot_tensor + (size_t)9 * n;
    float* o = rot_out + 2 + L0C + 3*n;
    o[0] = R[0]*v0 + R[1]*v1 + R[2]*v2;
    o[1] = R[3]*v0 + R[4]*v1 + R[5]*v2;
    o[2] = R[6]*v0 + R[7]*v1 + R[8]*v2;
  }
}

// ---------------- K3: dQ, ep = G@dQ, ener2; zero erep ----------------
__global__ __launch_bounds__(256) void k_coulomb(const float* __restrict__ S,
                                                 const float* __restrict__ G,
                                                 const float* __restrict__ rho,
                                                 const float* __restrict__ qneutral,
                                                 float* __restrict__ ep_all,
                                                 float* __restrict__ ener2_a,
                                                 float* __restrict__ erep_a){
  __shared__ float sRed[256];
  __shared__ float sdQ[64];
  __shared__ float sEp[64];
  const int mol = blockIdx.x;
  const int t = threadIdx.x;
  const int i = t >> 2, q4 = t & 3;
  const float* Sm = S   + (size_t)mol * 4096;
  const float* Gm = G   + (size_t)mol * 4096;
  const float* Rm = rho + (size_t)mol * 4096;

  float acc = 0.f;
  {
    const float4* S4 = reinterpret_cast<const float4*>(Sm + i*64 + q4*16);
    const float4* R4 = reinterpret_cast<const float4*>(Rm + i*64 + q4*16);
    #pragma unroll
    for (int m = 0; m < 4; ++m){
      float4 sv = S4[m], rv = R4[m];
      acc += sv.x*rv.x + sv.y*rv.y + sv.z*rv.z + sv.w*rv.w;
    }
  }
  sRed[t] = acc; __syncthreads();
  if (t < 64) sdQ[t] = qneutral[(size_t)mol*64 + t]
                       - (sRed[4*t] + sRed[4*t+1] + sRed[4*t+2] + sRed[4*t+3]);
  __syncthreads();

  float acc2 = 0.f;
  {
    const float4* G4 = reinterpret_cast<const float4*>(Gm + i*64 + q4*16);
    #pragma unroll
    for (int m = 0; m < 4; ++m){
      float4 gv = G4[m];
      int j0 = q4*16 + m*4;
      acc2 += gv.x*sdQ[j0] + gv.y*sdQ[j0+1] + gv.z*sdQ[j0+2] + gv.w*sdQ[j0+3];
    }
  }
  sRed[t] = acc2; __syncthreads();
  if (t < 64){
    float e = sRed[4*t] + sRed[4*t+1] + sRed[4*t+2] + sRed[4*t+3];
    sEp[t] = e;
    ep_all[(size_t)mol*64 + t] = e;
  }
  __syncthreads();
  if (t == 0){
    float s = 0.f;
    for (int j = 0; j < 64; ++j) s += sdQ[j] * sEp[j];
    ener2_a[mol] = 0.5f * s;
    erep_a[mol]  = 0.f;
  }
}

// ---------------- K4: Erep segment sum (sorted seg ids) ----------------
__global__ __launch_bounds__(256) void k_erep(const float* __restrict__ net,
                                              const int* __restrict__ g_rep,
                                              const int* __restrict__ seg_ids,
                                              float* __restrict__ erep_a){
  const int CH = 64;
  long tid = (long)blockIdx.x * 256 + threadIdx.x;
  long start = tid * CH;
  if (start >= NREPC) return;
  long end = start + CH; if (end > NREPC) end = NREPC;
  int cur = seg_ids[start];
  float acc = 0.f;
  for (long e = start; e < end; ++e){
    int sgid = seg_ids[e];
    if (sgid != cur){ atomicAdd(&erep_a[cur], acc); cur = sgid; acc = 0.f; }
    acc += net[g_rep[e]];
  }
  atomicAdd(&erep_a[cur], acc);
}

// ---------------- LDS matmul helper (64x64, stride MS), A symmetric ------
__device__ __forceinline__ void mm_symA(float (*__restrict__ D)[MS],
                                        const float (*__restrict__ A)[MS],
                                        const float (*__restrict__ B)[MS],
                                        float alpha, float diag, int t){
  const int r0 = (t & 15) << 2, c0 = (t >> 4) << 2;
  float acc[4][4];
  #pragma unroll
  for (int i = 0; i < 4; ++i)
    #pragma unroll
    for (int j = 0; j < 4; ++j) acc[i][j] = 0.f;
  #pragma unroll 8
  for (int k = 0; k < 64; ++k){
    float4 av = *reinterpret_cast<const float4*>(&A[k][r0]);
    float4 bv = *reinterpret_cast<const float4*>(&B[k][c0]);
    float a_[4] = {av.x, av.y, av.z, av.w};
    float b_[4] = {bv.x, bv.y, bv.z, bv.w};
    #pragma unroll
    for (int i = 0; i < 4; ++i)
      #pragma unroll
      for (int j = 0; j < 4; ++j)
        acc[i][j] += a_[i] * b_[j];
  }
  #pragma unroll
  for (int i = 0; i < 4; ++i)
    #pragma unroll
    for (int j = 0; j < 4; ++j)
      D[r0+i][c0+j] = alpha * acc[i][j] + ((r0+i) == (c0+j) ? diag : 0.f);
}

// ---- K5: NS X=S^{-1/2} (6 mm) + fockp = X F X + C2 = X E S X (4 mm) -----
__global__ __launch_bounds__(256, 2) void k_ns(const float* __restrict__ S,
                                               const int* __restrict__ g_oper,
                                               const float* __restrict__ rot_out,
                                               const float* __restrict__ ep_all,
                                               float* __restrict__ fockp_all,
                                               float* __restrict__ C2_all){
  __shared__ float M[4][64][MS];
  __shared__ float sEp[64];
  const int t   = threadIdx.x;
  const int mol = blockIdx.x;
  const float* Sm = S + (size_t)mol * 4096;
  const int*   gm = g_oper + (size_t)mol * 4096;

  // init: M0 = S, M2 = 3I - S
  #pragma unroll
  for (int m = 0; m < 16; ++m){
    int e = t + (m << 8);
    int i = e >> 6, j = e & 63;
    float s = Sm[e];
    M[0][i][j] = s;
    M[2][i][j] = ((i == j) ? 3.f : 0.f) - s;
  }
  if (t < 64) sEp[t] = ep_all[(size_t)mol*64 + t];
  __syncthreads();
  mm_symA(M[3], M[0], M[2], 0.5f, 0.f, t);          // Y1 = 0.5 S (3I-S)
  #pragma unroll
  for (int m = 0; m < 16; ++m){
    int e = t + (m << 8);
    M[1][e >> 6][e & 63] = 0.5f * M[2][e >> 6][e & 63];  // Z1 = 0.5(3I-S)
  }
  __syncthreads();
  // iter2: Y=M3, Z=M1
  mm_symA(M[0], M[1], M[3], -1.f, 3.f, t); __syncthreads();  // T2 = 3I - Z1*Y1
  mm_symA(M[2], M[3], M[0], 0.5f, 0.f, t); __syncthreads();  // Y2 = 0.5*Y1*T2
  mm_symA(M[3], M[0], M[1], 0.5f, 0.f, t); __syncthreads();  // Z2 = 0.5*T2*Z1
  // iter3 (Z-only): Y=M2, Z=M3
  mm_symA(M[1], M[3], M[2], -1.f, 3.f, t); __syncthreads();  // T3 = 3I - Z2*Y2
  mm_symA(M[0], M[1], M[3], 0.5f, 0.f, t); __syncthreads();  // X  = 0.5*T3*Z2
  // buffers now: M0 = X; M1..M3 free

  // --- H gather -> M1 ---
  #pragma unroll
  for (int m = 0; m < 16; ++m){
    int e = t + (m << 8);
    M[1][e >> 6][e & 63] = rot_out[gm[e]];
  }
  __syncthreads();
  // --- F -> M2: F_ij = 0.5(H_ij + H_ji) - 0.5 S_ij (ep_i + ep_j) ---
  #pragma unroll
  for (int m = 0; m < 16; ++m){
    int e = t + (m << 8);
    int i = e >> 6, j = e & 63;
    M[2][i][j] = 0.5f*(M[1][i][j] + M[1][j][i]) - 0.5f*Sm[e]*(sEp[i] + sEp[j]);
  }
  __syncthreads();
  mm_symA(M[3], M[2], M[0], 1.f, 0.f, t); __syncthreads();  // P1 = F*X
  mm_symA(M[1], M[0], M[3], 1.f, 0.f, t); __syncthreads();  // fockp = X*P1
  #pragma unroll
  for (int m = 0; m < 16; ++m){
    int e = t + (m << 8);
    fockp_all[(size_t)mol * 4096 + e] = M[1][e >> 6][e & 63];
  }
  // --- reload S -> M2 ---
  #pragma unroll
  for (int m = 0; m < 16; ++m){
    int e = t + (m << 8);
    M[2][e >> 6][e & 63] = Sm[e];
  }
  __syncthreads();
  mm_symA(M[3], M[2], M[0], 1.f, 0.f, t); __syncthreads();  // C1 = S*X
  // EC1 in place: row-scale by ep
  #pragma unroll
  for (int m = 0; m < 16; ++m){
    int e = t + (m << 8);
    int i = e >> 6, j = e & 63;
    M[3][i][j] *= sEp[i];
  }
  __syncthreads();
  mm_symA(M[1], M[0], M[3], 1.f, 0.f, t); __syncthreads();  // C2 = X*(E C1)
  #pragma unroll
  for (int m = 0; m < 16; ++m){
    int e = t + (m << 8);
    C2_all[(size_t)mol * 4096 + e] = M[1][e >> 6][e & 63];
  }
}

// ---------------- K6: split-row XOR-block Jacobi + split epilogue ---------
__global__ __launch_bounds__(64, 2) void k_jac(const float* __restrict__ fockp_all,
                                               const float* __restrict__ C2_all,
                                               const float* __restrict__ ener2_a,
                                               const float* __restrict__ erep_a,
                                               float* __restrict__ out){
  __shared__ float Bl[64 * 68];         // C2 staging (pre-loaded before sweeps)
  const int lane = threadIdx.x;
  const int mol  = blockIdx.x;
  const float* Am = fockp_all + (size_t)mol * 4096;
  const float* Cm = C2_all    + (size_t)mol * 4096;
  const int pid  = lane & 31;
  const int half = lane >> 5;

  // --- direct split-layout load: proc pid = lanes (pid, pid+32);
  //     lane holds rows [half*32, half*32+32) of cols A=pid, B=32+pid ---
  float Ac[32], Bc[32];
  float csA = 0.f, csB = 0.f;
  #pragma unroll
  for (int i = 0; i < 32; ++i){
    float a = Am[(half*32 + i)*64 + pid];
    float b = Am[(half*32 + i)*64 + 32 + pid];
    Ac[i] = a; Bc[i] = b;
    csA += fabsf(a); csB += fabsf(b);
  }
  // --- stage C2 into LDS now; latency hides under the Jacobi sweeps ---
  #pragma unroll
  for (int i = 0; i < 64; ++i) Bl[i*68 + lane] = Cm[i*64 + lane];

  // --- Gershgorin shift: mu = 1.02 * max col abs-sum; add to diagonals ---
  csA += __shfl_xor(csA, 32);
  csB += __shfl_xor(csB, 32);
  float mu = fmaxf(csA, csB);
  #pragma unroll
  for (int d = 1; d < 32; d <<= 1) mu = fmaxf(mu, __shfl_xor(mu, d));
  mu *= 1.02f;
  #pragma unroll
  for (int i = 0; i < 32; ++i){
    Ac[i] += (half == 0 && i == pid) ? mu : 0.f;
    Bc[i] += (half == 1 && i == pid) ? mu : 0.f;
  }

  // --- XOR-block one-sided Jacobi (layout-invariant schedule);
  //     three-shear rotations, 4-way dot chains, native rcp/rsq ---
  for (int sweep = 0; sweep < 3; ++sweep){
    float a0 = 0.f, a1 = 0.f, a2 = 0.f, a3 = 0.f;
    float b0 = 0.f, b1 = 0.f, b2 = 0.f, b3 = 0.f;
    #pragma unroll
    for (int i = 0; i < 32; i += 4){
      a0 = fmaf(Ac[i],   Ac[i],   a0); a1 = fmaf(Ac[i+1], Ac[i+1], a1);
      a2 = fmaf(Ac[i+2], Ac[i+2], a2); a3 = fmaf(Ac[i+3], Ac[i+3], a3);
      b0 = fmaf(Bc[i],   Bc[i],   b0); b1 = fmaf(Bc[i+1], Bc[i+1], b1);
      b2 = fmaf(Bc[i+2], Bc[i+2], b2); b3 = fmaf(Bc[i+3], Bc[i+3], b3);
    }
    float alpha = (a0 + a1) + (a2 + a3);
    float beta  = (b0 + b1) + (b2 + b3);
    alpha += __shfl_xor(alpha, 32);
    beta  += __shfl_xor(beta, 32);

    unsigned long long any = 0ULL;
    for (int j = 5; j >= 0; --j){
      const int M = 1 << j;
      for (int k = 0; k < M; ++k){
        float g0 = 0.f, g1 = 0.f, g2 = 0.f, g3 = 0.f;
        #pragma unroll
        for (int i = 0; i < 32; i += 4){
          g0 = fmaf(Ac[i],   Bc[i],   g0);
          g1 = fmaf(Ac[i+1], Bc[i+1], g1);
          g2 = fmaf(Ac[i+2], Bc[i+2], g2);
          g3 = fmaf(Ac[i+3], Bc[i+3], g3);
        }
        float gamma = (g0 + g1) + (g2 + g3);
        gamma += __shfl_xor(gamma, 32);
        bool rot = (gamma * gamma) > (1e-9f * alpha * beta);
        unsigned long long bal = __ballot(rot);
        any |= bal;
        if (bal != 0ULL){
          // angle chain on native rcp/rsq (Jacobi self-corrects ULP error)
          float tau = (beta - alpha) * 0.5f * __builtin_amdgcn_rcpf(gamma);
          float tq  = copysignf(1.f, tau) *
                      __builtin_amdgcn_rcpf(fabsf(tau) + __builtin_amdgcn_sqrtf(fmaf(tau, tau, 1.f)));
          float c = __builtin_amdgcn_rsqf(fmaf(tq, tq, 1.f));
          float s = tq * c;
          float th = s * __builtin_amdgcn_rcpf(1.f + c);   // tan(theta/2)
          if (!rot){ c = 1.f; s = 0.f; th = 0.f; }
          float na = c*c*alpha + s*s*beta - 2.f*c*s*gamma;
          float nb = s*s*alpha + c*c*beta + 2.f*c*s*gamma;
          alpha = na; beta = nb;
          // three-shear rotation: exact det-1, 3 FMA per element pair
          #pragma unroll
          for (int i = 0; i < 32; ++i) Ac[i] = fmaf(-th, Bc[i], Ac[i]);
          #pragma unroll
          for (int i = 0; i < 32; ++i) Bc[i] = fmaf( s,  Ac[i], Bc[i]);
          #pragma unroll
          for (int i = 0; i < 32; ++i) Ac[i] = fmaf(-th, Bc[i], Ac[i]);
        }
        if (k < M - 1){
          int e  = k ^ (k >> 1);
          int e2 = (k + 1) ^ ((k + 1) >> 1);
          int mig = e ^ e2;
          #pragma unroll
          for (int i = 0; i < 32; ++i) Bc[i] = __shfl_xor(Bc[i], mig);
          beta = __shfl_xor(beta, mig);
        } else if (j > 0){
          const int Mp = M >> 1;
          const bool hb = (pid & Mp) != 0;
          #pragma unroll
          for (int i = 0; i < 32; ++i){
            float send = hb ? Ac[i] : Bc[i];
            float recv = __shfl_xor(send, Mp);
            Ac[i] = hb ? Bc[i] : Ac[i];
            Bc[i] = recv;
          }
          float sendb = hb ? alpha : beta;
          float recvb = __shfl_xor(sendb, Mp);
          alpha = hb ? beta : alpha;
          beta  = recvb;
        }
      }
    }
    if (any == 0ULL) break;
  }

  // --- split-form epilogue: NO reassembly, no w[64] ---
  float nA0 = 0.f, nA1 = 0.f, nB0 = 0.f, nB1 = 0.f;
  #pragma unroll
  for (int i = 0; i < 32; i += 2){
    nA0 = fmaf(Ac[i],   Ac[i],   nA0);
    nA1 = fmaf(Ac[i+1], Ac[i+1], nA1);
    nB0 = fmaf(Bc[i],   Bc[i],   nB0);
    nB1 = fmaf(Bc[i+1], Bc[i+1], nB1);
  }
  float nA = nA0 + nA1, nB = nB0 + nB1;
  nA += __shfl_xor(nA, 32);
  nB += __shfl_xor(nB, 32);
  float myLamS = half ? sqrtf(nB) : sqrtf(nA);
  float myLam  = myLamS - mu;

  int rank = 0;
  for (int k = 0; k < 64; ++k){
    float lk = __shfl(myLam, k);
    rank += (lk < myLam || (lk == myLam && k < lane)) ? 1 : 0;
  }
  out[(size_t)mol*65 + 1 + rank] = myLam;

  float occf = (rank < 32) ? 1.f : 0.f;
  float slam = occf * myLam;
  #pragma unroll
  for (int d = 1; d < 64; d <<= 1) slam += __shfl_xor(slam, d);

  // per-column scales: col A's scale lives on lane pid, col B's on lane 32+pid
  float myScale = occf / myLamS;
  float sA = __shfl(myScale, pid);
  float sB = __shfl(myScale, 32 + pid);
  #pragma unroll
  for (int i = 0; i < 32; ++i){ Ac[i] *= sA; Bc[i] *= sB; }

  __syncthreads();   // C2 staging visible (single wave: cheap)

  // quadratic form in split layout
  const int myB = half * 32;       // my row/col block offset
  const int otB = 32 - myB;        // partner block offset
  float pv[32];
  float term = 0.f;
  #pragma unroll
  for (int i = 0; i < 32; ++i) pv[i] = __shfl_xor(Ac[i], 32);
  #pragma unroll 4
  for (int i = 0; i < 32; ++i){
    const float* row = &Bl[(myB + i) * 68];
    float d = 0.f;
    #pragma unroll
    for (int k = 0; k < 32; k += 4){
      float4 c1 = *reinterpret_cast<const float4*>(&row[myB + k]);
      d = fmaf(c1.x, Ac[k], d);   d = fmaf(c1.y, Ac[k+1], d);
      d = fmaf(c1.z, Ac[k+2], d); d = fmaf(c1.w, Ac[k+3], d);
      float4 c2 = *reinterpret_cast<const float4*>(&row[otB + k]);
      d = fmaf(c2.x, pv[k], d);   d = fmaf(c2.y, pv[k+1], d);
      d = fmaf(c2.z, pv[k+2], d); d = fmaf(c2.w, pv[k+3], d);
    }
    term = fmaf(Ac[i], d, term);
  }
  #pragma unroll
  for (int i = 0; i < 32; ++i) pv[i] = __shfl_xor(Bc[i], 32);
  #pragma unroll 4
  for (int i = 0; i < 32; ++i){
    const float* row = &Bl[(myB + i) * 68];
    float d = 0.f;
    #pragma unroll
    for (int k = 0; k < 32; k += 4){
      float4 c1 = *reinterpret_cast<const float4*>(&row[myB + k]);
      d = fmaf(c1.x, Bc[k], d);   d = fmaf(c1.y, Bc[k+1], d);
      d = fmaf(c1.z, Bc[k+2], d); d = fmaf(c1.w, Bc[k+3], d);
      float4 c2 = *reinterpret_cast<const float4*>(&row[otB + k]);
      d = fmaf(c2.x, pv[k], d);   d = fmaf(c2.y, pv[k+1], d);
      d = fmaf(c2.z, pv[k+2], d); d = fmaf(c2.w, pv[k+3], d);
    }
    term = fmaf(Bc[i], d, term);
  }
  #pragma unroll
  for (int d2 = 1; d2 < 64; d2 <<= 1) term += __shfl_xor(term, d2);

  if (lane == 0){
    out[(size_t)mol*65] = 2.f*slam + 2.f*term + ener2_a[mol] + erep_a[mol];
  }
}

// ---------------------------------------------------------------------------
extern "C" void kernel_launch(void* const* d_in, const int* in_sizes, int n_in,
                              void* d_out, int out_size, void* d_ws, size_t ws_size,
                              hipStream_t stream){
  (void)in_sizes; (void)n_in; (void)out_size; (void)ws_size;
  const float* A          = (const float*)d_in[0];
  const float* b          = (const float*)d_in[1];
  const float* coeffs     = (const float*)d_in[2];
  const float* rot_tensor = (const float*)d_in[3];
  const float* S          = (const float*)d_in[4];
  const float* G          = (const float*)d_in[5];
  const float* rho        = (const float*)d_in[6];
  const float* qneutral   = (const float*)d_in[7];
  const int* g_rot_direct = (const int*)d_in[9];
  const int* g_rot        = (const int*)d_in[10];
  const int* g_oper       = (const int*)d_in[11];
  const int* g_rep        = (const int*)d_in[12];
  const int* seg_ids      = (const int*)d_in[13];
  float* out = (float*)d_out;

  // ws layout (floats): 5.35MB scalars + fockp 32MB + C2 32MB ~= 72.5MB
  float* W         = (float*)d_ws;
  float* net       = W;                    // 500000
  float* rot_out   = W + 500000;           // 700002 (padded to 700004)
  float* ep_all    = W + 1200004;          // 2048*64
  float* ener2_a   = W + 1331076;          // 2048
  float* erep_a    = W + 1333124;          // 2048
  float* fockp_all = W + 1335172;          // 2048*4096
  float* C2_all    = W + 9723780;          // 2048*4096 (ends 18112388)

  k_netvals<<<(NSPC*16)/256, 256, 0, stream>>>(A, b, coeffs, net);
  k_rot<<<(L0C + NROTC + 255)/256, 256, 0, stream>>>(net, rot_tensor, g_rot_direct, g_rot, rot_out);
  k_coulomb<<<NMOLC, 256, 0, stream>>>(S, G, rho, qneutral, ep_all, ener2_a, erep_a);
  k_erep<<<((NREPC + 63)/64 + 255)/256, 256, 0, stream>>>(net, g_rep, seg_ids, erep_a);
  k_ns<<<NMOLC, 256, 0, stream>>>(S, g_oper, rot_out, ep_all, fockp_all, C2_all);
  k_jac<<<NMOLC, 64, 0, stream>>>(fockp_all, C2_all, ener2_a, erep_a, out);
}